// Round 10
// baseline (282.192 us; speedup 1.0000x reference)
//
#include <hip/hip_runtime.h>
#include <hip/hip_bf16.h>
#include <math.h>

#define NEGV -1e30f
#define LN2F 0.6931471805599453f

// B=16, T=800, D=512, V=4000 (padded to 4096), Lmax=100, S=201
// M = B*T = 12800 rows.
// GEMM operands are stored PRE-SWIZZLED in MFMA fragment order:
//   A2[rb<100][it<16][wm<2][mi<4][lane<64][8]  (row = rb*128+wm*64+mi*16+(lane&15), k = it*32+(lane>>4)*8)
//   W2[ct<32][it<16][wn<2][ni<4][lane<64][8]   (col = ct*128+wn*64+ni*16+(lane&15), same k)
// so every fragment load is one coalesced global_load_dwordx4 -> no LDS, no barriers.

typedef __attribute__((ext_vector_type(8))) short bf16x8;
typedef __attribute__((ext_vector_type(4))) float f32x4;

__device__ __forceinline__ short f2bf(float x) {
    __hip_bfloat16 h = __float2bfloat16(x);
    return __builtin_bit_cast(short, h);
}

// wave-wide shift-up-by-1 with zero fill on the VALU (DPP wave_shr:1)
__device__ __forceinline__ float shup1(float x) {
    return __builtin_bit_cast(float,
        __builtin_amdgcn_update_dpp(0, __builtin_bit_cast(int, x),
                                    0x138, 0xf, 0xf, true));
}

// ---------------------------------------------------------------------------
// prep: W->W2 fragment-swizzle (blocks 0..1023), hs->A2 fragment-swizzle
// (1024..4223), setup tables (4224).
// ---------------------------------------------------------------------------
__global__ __launch_bounds__(256) void prep(
    const float* __restrict__ hs, const float* __restrict__ W,
    const float* __restrict__ bias, const int* __restrict__ ys,
    short* __restrict__ W2, short* __restrict__ A2,
    float* __restrict__ biasp, unsigned char* __restrict__ M,
    unsigned char* __restrict__ canon, float* __restrict__ lse_sum,
    float* __restrict__ out)
{
    __shared__ float tile[32][65];
    __shared__ unsigned char mapl[4096];
    const int bx = blockIdx.x, tid = threadIdx.x;

    if (bx < 1024) {
        // ---- W [512][4000] -> W2 fragment layout (zero-pad cols>=4000) ----
        const int n0 = (bx & 63) * 64;     // 64-col group
        const int k0 = (bx >> 6) * 32;     // 32-k group
        #pragma unroll
        for (int p = 0; p < 8; p++) {
            int idx = p * 256 + tid;
            int k = idx >> 6, n = idx & 63;
            int gn = n0 + n;
            tile[k][n] = (gn < 4000) ? W[(size_t)(k0 + k) * 4000 + gn] : 0.0f;
        }
        __syncthreads();
        // write 4 chunks of 64 lanes x 16B, coalesced
        const int nn = tid >> 6, lane = tid & 63;
        const int l16 = lane & 15, quad = lane >> 4;
        const int ct = n0 >> 7, wn = (n0 >> 6) & 1, it = k0 >> 5;
        size_t chunk = ((((size_t)ct * 16 + it) * 2 + wn) * 4 + nn) * 64 + lane;
        bf16x8 r;
        #pragma unroll
        for (int j = 0; j < 8; j++) r[j] = f2bf(tile[quad * 8 + j][nn * 16 + l16]);
        *(bf16x8*)(W2 + chunk * 8) = r;
    } else if (bx < 4224) {
        // ---- hs fp32 -> A2 fragment layout ----
        int g = (bx - 1024) * 256 + tid;           // 0..819199
        int lane = g & 63, mi = (g >> 6) & 3, wm = (g >> 8) & 1;
        int it = (g >> 9) & 15, rb = g >> 13;
        int row = rb * 128 + wm * 64 + mi * 16 + (lane & 15);
        int k = it * 32 + (lane >> 4) * 8;
        const float* src = hs + (size_t)row * 512 + k;
        float4 u = *(const float4*)src;
        float4 v = *(const float4*)(src + 4);
        bf16x8 r;
        r[0] = f2bf(u.x); r[1] = f2bf(u.y); r[2] = f2bf(u.z); r[3] = f2bf(u.w);
        r[4] = f2bf(v.x); r[5] = f2bf(v.y); r[6] = f2bf(v.z); r[7] = f2bf(v.w);
        *(bf16x8*)(A2 + (size_t)g * 8) = r;
    } else {
        for (int b = 0; b < 16; b++) {
            for (int i = tid; i < 1024; i += 256)
                ((unsigned int*)mapl)[i] = 0xFFFFFFFFu;
            __syncthreads();
            if (tid == 0) mapl[0] = 0;
            __syncthreads();
            if (tid < 100) mapl[ys[b * 100 + tid]] = (unsigned char)(tid + 1);
            __syncthreads();
            for (int i = tid; i < 1024; i += 256)
                ((unsigned int*)(M + (size_t)b * 4096))[i] = ((const unsigned int*)mapl)[i];
            if (tid < 128) {
                int colc = (tid >= 1 && tid <= 100) ? ys[b * 100 + tid - 1] : 0;
                canon[b * 128 + tid] = mapl[colc];
            }
            __syncthreads();
        }
        for (int i = tid; i < 4096; i += 256)
            biasp[i] = (i < 4000) ? bias[i] : NEGV;
        for (int i = tid; i < 12800; i += 256)
            lse_sum[i] = 0.0f;
        if (tid == 0) out[0] = 0.0f;
    }
}

// ---------------------------------------------------------------------------
// Streaming-sumexp GEMM, LDS-free: fragment loads direct global->VGPR.
// grid (100, 32) x 256 (4 waves: wm=w>>1 picks 64 rows, wn=w&1 picks 64 cols).
// No barriers; compiler pipelines loads with vmcnt.
// ---------------------------------------------------------------------------
__global__ __launch_bounds__(256) void lse_mfma(
    const short* __restrict__ A2,     // fragment layout
    const short* __restrict__ W2,     // fragment layout
    const float* __restrict__ biasp,  // [4096]
    const unsigned char* __restrict__ M,  // [16][4096]
    float* __restrict__ lse_sum,      // [12800]
    __hip_bfloat16* __restrict__ Praw)// [12800][128]
{
    const int tid = threadIdx.x;
    const int w = tid >> 6, lane = tid & 63;
    const int quad = lane >> 4, l16 = lane & 15;
    const int wm = w >> 1, wn = w & 1;
    const int row0 = blockIdx.x * 128;
    const int col0 = blockIdx.y * 128;

    // it stride = 2*4*64*8 = 4096 shorts; mi/ni stride = 64*8 = 512 shorts
    const short* Abase = A2 + ((size_t)blockIdx.x * 16 * 2 + wm) * 4 * 64 * 8 + lane * 8;
    const short* Bbase = W2 + ((size_t)blockIdx.y * 16 * 2 + wn) * 4 * 64 * 8 + lane * 8;

    f32x4 acc[4][4];
    #pragma unroll
    for (int mi = 0; mi < 4; mi++)
        #pragma unroll
        for (int ni = 0; ni < 4; ni++) acc[mi][ni] = (f32x4){0.f,0.f,0.f,0.f};

    #pragma unroll 4
    for (int it = 0; it < 16; it++) {
        bf16x8 af[4], bfr[4];
        #pragma unroll
        for (int mi = 0; mi < 4; mi++)
            af[mi] = *(const bf16x8*)(Abase + (size_t)it * 4096 + mi * 512);
        #pragma unroll
        for (int ni = 0; ni < 4; ni++)
            bfr[ni] = *(const bf16x8*)(Bbase + (size_t)it * 4096 + ni * 512);
        #pragma unroll
        for (int mi = 0; mi < 4; mi++)
            #pragma unroll
            for (int ni = 0; ni < 4; ni++)
                acc[mi][ni] = __builtin_amdgcn_mfma_f32_16x16x32_bf16(
                    af[mi], bfr[ni], acc[mi][ni], 0, 0, 0);
    }

    // epilogue: sumexp partials + scatter label-column logits
    const int b0 = row0 / 800;
    const int b1 = (b0 + 1 < 16) ? b0 + 1 : 15;
    const int bbound = (b0 + 1) * 800;
    float s[16];
    #pragma unroll
    for (int i = 0; i < 16; i++) s[i] = 0.0f;
    #pragma unroll
    for (int ni = 0; ni < 4; ni++) {
        int col = col0 + wn * 64 + ni * 16 + l16;
        float bj = biasp[col];
        unsigned char sl0 = M[(size_t)b0 * 4096 + col];
        unsigned char sl1 = M[(size_t)b1 * 4096 + col];
        #pragma unroll
        for (int mi = 0; mi < 4; mi++) {
            #pragma unroll
            for (int r = 0; r < 4; r++) {
                int row = row0 + wm * 64 + mi * 16 + quad * 4 + r;
                float v = acc[mi][ni][r] + bj;
                s[mi * 4 + r] += __expf(v);
                unsigned char sl = (row < bbound) ? sl0 : sl1;
                if (sl != 255)
                    Praw[(size_t)row * 128 + sl] = __float2bfloat16(v);
            }
        }
    }
    #pragma unroll
    for (int off = 1; off < 16; off <<= 1)
        #pragma unroll
        for (int i = 0; i < 16; i++) s[i] += __shfl_xor(s[i], off);
    if (l16 == 0) {
        #pragma unroll
        for (int mi = 0; mi < 4; mi++)
            #pragma unroll
            for (int r = 0; r < 4; r++)
                atomicAdd(&lse_sum[row0 + wm * 64 + mi * 16 + quad * 4 + r],
                          s[mi * 4 + r]);
    }
}

// ---------------------------------------------------------------------------
// pexp: PE[row][s] = exp(Praw[row][st[s]]) * rcp(lse_sum[row]) * 2^11, float.
// ---------------------------------------------------------------------------
__global__ __launch_bounds__(256) void pexp(
    const __hip_bfloat16* __restrict__ Praw,  // [12800][128]
    const float* __restrict__ lse_sum,        // [12800]
    const unsigned char* __restrict__ canon,  // [16][128]
    float* __restrict__ PE)                   // [12800][208]
{
    __shared__ unsigned char st[224];
    __shared__ float scs[16];
    const int bp = blockIdx.x;           // 0..799
    const int b = bp / 50, rr = bp - b * 50;
    const int tid = threadIdx.x;
    const unsigned char* cb = canon + b * 128;
    if (tid < 224) {
        int idx = (tid + 1) >> 1;
        st[tid] = (tid & 1) ? cb[idx < 128 ? idx : 127] : (unsigned char)0;
    }
    const int row0 = b * 800 + rr * 16;
    if (tid < 16) scs[tid] = __builtin_amdgcn_rcpf(lse_sum[row0 + tid]) * 2048.0f;
    __syncthreads();
    for (int item = tid; item < 832; item += 256) {   // 16 rows x 52 float4
        int i = item / 52, sg = item - i * 52;
        int row = row0 + i;
        const __hip_bfloat16* pr = Praw + (size_t)row * 128;
        float sc = scs[i];
        int s0 = sg * 4;
        float4 o;
        o.x = (s0 + 0 <= 200) ? __expf(__bfloat162float(pr[st[s0 + 0]])) * sc : 0.f;
        o.y = (s0 + 1 <= 200) ? __expf(__bfloat162float(pr[st[s0 + 1]])) * sc : 0.f;
        o.z = (s0 + 2 <= 200) ? __expf(__bfloat162float(pr[st[s0 + 2]])) * sc : 0.f;
        o.w = (s0 + 3 <= 200) ? __expf(__bfloat162float(pr[st[s0 + 3]])) * sc : 0.f;
        *(float4*)&PE[(size_t)row * 208 + s0] = o;
    }
}

// ---------------------------------------------------------------------------
// CTC forward DP, probability domain, two steps fused per iteration.
// Staging waves: pure coalesced float4 copies of PE rows into LDS.
// DP wave: 2 contiguous ds_read_b128 per pair (prefetched), DPP neighbors.
// ---------------------------------------------------------------------------
__global__ __launch_bounds__(256) void ctc_dp(
    const float* __restrict__ PE,             // [12800][208]
    const int* __restrict__ hlens,
    const int* __restrict__ ys,
    const int* __restrict__ ylens,
    float* __restrict__ out)
{
    const int b = blockIdx.x, tid = threadIdx.x;
    const int w = tid >> 6, lane = tid & 63;
    __shared__ float emS[2][13376];   // 64 rows x 208 + pad; ~107 KB
    __shared__ float sA[256];

    const float* Pb = PE + (size_t)b * 800 * 208;
    const int hl = hlens[b], L = ylens[b];
    const int t_stop = hl - 1;
    const int C = (t_stop + 63) >> 6;

    const int yb = b * 100;
    float kA = 0.f, kB = 0.f, kH = 0.f;
    if (lane >= 1 && 2 * lane <= 99)
        kA = (ys[yb + 2 * lane] != ys[yb + 2 * lane - 1]) ? 1.f : 0.f;
    if (2 * lane + 1 <= 99)
        kB = (ys[yb + 2 * lane + 1] != ys[yb + 2 * lane]) ? 1.f : 0.f;
    if (lane >= 1 && 2 * lane - 1 <= 99)
        kH = (ys[yb + 2 * lane - 1] != ys[yb + 2 * lane - 2]) ? 1.f : 0.f;
    const float m0  = (lane <= 50) ? 1.f : 0.f;
    const float m13 = (lane <= 49) ? 1.f : 0.f;

    float a0 = 0.f, a1 = 0.f, a2 = 0.f, a3 = 0.f;
    if (w == 0 && lane == 0) {
        a0 = Pb[0];
        a1 = Pb[1];
    }
    int kacc = 0;

    // stage chunk 0: rows t = 1..64 (all 256 threads), 52 float4 per row
    for (int idx = tid; idx < 3328; idx += 256) {
        int i = idx / 52, sg = idx - i * 52;
        int tr = 1 + i; if (tr > 799) tr = 799;
        *(float4*)&emS[0][i * 208 + sg * 4] =
            *(const float4*)&Pb[(size_t)tr * 208 + sg * 4];
    }
    __syncthreads();

    for (int ch = 0; ch < C; ch++) {
        if (w > 0) {
            int nc = ch + 1;
            if (nc < C) {
                float* dst = emS[nc & 1];
                const int tbase = 64 * nc + 1;
                for (int idx = tid - 64; idx < 3328; idx += 192) {
                    int i = idx / 52, sg = idx - i * 52;
                    int tr = tbase + i; if (tr > 799) tr = 799;
                    *(float4*)&dst[i * 208 + sg * 4] =
                        *(const float4*)&Pb[(size_t)tr * 208 + sg * 4];
                }
            }
        } else {
            const float* bb = emS[ch & 1];
            const int t0 = 64 * ch + 1;
            const int soff = 4 * lane;
            if (t0 + 63 <= t_stop) {
                // ---- fast path: 32 fused pairs, 2 b128 reads each ----
                f32x4 e = *(const f32x4*)&bb[0 * 208 + soff];
                f32x4 f = *(const f32x4*)&bb[1 * 208 + soff];
                #pragma unroll
                for (int k = 0; k < 32; k++) {
                    f32x4 en = (f32x4){0.f,0.f,0.f,0.f};
                    f32x4 fn = (f32x4){0.f,0.f,0.f,0.f};
                    if (k < 31) {
                        en = *(const f32x4*)&bb[(2 * k + 2) * 208 + soff];
                        fn = *(const f32x4*)&bb[(2 * k + 3) * 208 + soff];
                    }
                    float pht = shup1(e[3]);
                    float h1 = shup1(a3);
                    float h2 = shup1(a2);
                    float h3 = shup1(a1);
                    float tm1 = fmaf(kH, h3, h1 + h2);
                    float t0v = a0 + h1;
                    float t1v = fmaf(kA, h1, a1 + a0);
                    float t2v = a2 + a1;
                    float t3v = fmaf(kB, a1, a3 + a2);
                    float um1 = pht * tm1;
                    float u0 = e[0] * t0v, u1 = e[1] * t1v;
                    float u2 = e[2] * t2v, u3 = e[3] * t3v;
                    a0 = (f[0] * (u0 + um1)) * m0;
                    a1 = (f[1] * fmaf(kA, um1, u1 + u0)) * m13;
                    a2 = (f[2] * (u2 + u1)) * m13;
                    a3 = (f[3] * fmaf(kB, u1, u3 + u2)) * m13;
                    if ((k & 7) == 7) {
                        int tc = t0 + 2 * k + 1;
                        float lm = fmaxf(fmaxf(a0, a1), fmaxf(a2, a3));
                        int sa1 = (2 * L < tc) ? 2 * L : tc;
                        int sa2 = (int)(2.0f * L * tc / hl);
                        float v1 = __shfl(lm, sa1 >> 2);
                        float v2 = __shfl(lm, sa2 >> 2);
                        float av = fmaxf(v1, v2);
                        int eb = (__float_as_int(av) >> 23) & 0xFF;
                        if (eb != 0 && eb != 255) {
                            int e2i = eb - 127;
                            kacc += e2i;
                            float sc = __int_as_float((127 - e2i) << 23);
                            a0 *= sc; a1 *= sc; a2 *= sc; a3 *= sc;
                        }
                    }
                    e = en; f = fn;
                }
            } else {
                // ---- slow tail: single steps ----
                for (int t = t0; t <= t_stop; t++) {
                    if ((t & 15) == 0) {
                        float lm = fmaxf(fmaxf(a0, a1), fmaxf(a2, a3));
                        int sa1 = (2 * L < t) ? 2 * L : t;
                        int sa2 = (int)(2.0f * L * t / hl);
                        float v1 = __shfl(lm, sa1 >> 2);
                        float v2 = __shfl(lm, sa2 >> 2);
                        float av = fmaxf(v1, v2);
                        int eb = (__float_as_int(av) >> 23) & 0xFF;
                        if (eb != 0 && eb != 255) {
                            int e2i = eb - 127;
                            kacc += e2i;
                            float sc = __int_as_float((127 - e2i) << 23);
                            a0 *= sc; a1 *= sc; a2 *= sc; a3 *= sc;
                        }
                    }
                    f32x4 e = *(const f32x4*)&bb[(t - t0) * 208 + soff];
                    float p3 = shup1(a3);
                    float n0 = (a0 + p3) * e[0];
                    float n1 = fmaf(kA, p3, a1 + a0) * e[1];
                    float n2 = (a2 + a1) * e[2];
                    float n3 = fmaf(kB, a1, a3 + a2) * e[3];
                    a0 = n0 * m0; a1 = n1 * m13; a2 = n2 * m13; a3 = n3 * m13;
                }
            }
        }
        __syncthreads();
    }

    if (w == 0) {
        sA[lane * 4 + 0] = a0; sA[lane * 4 + 1] = a1;
        sA[lane * 4 + 2] = a2; sA[lane * 4 + 3] = a3;
    }
    __syncthreads();

    if (tid == 0) {
        int idx = 2 * L;
        float s = sA[idx] + sA[idx - 1];
        float la = __logf(s) + (float)(kacc - 11 * hl) * LN2F;
        float loss = -la;
        if (!isfinite(loss) || loss >= 1e29f) loss = 0.0f;
        atomicAdd(out, loss * 0.0625f);
    }
}

// ---------------------------------------------------------------------------
extern "C" void kernel_launch(void* const* d_in, const int* in_sizes, int n_in,
                              void* d_out, int out_size, void* d_ws, size_t ws_size,
                              hipStream_t stream)
{
    const float* hs    = (const float*)d_in[0];   // [16,800,512]
    const float* W     = (const float*)d_in[1];   // [512,4000]
    const float* bias  = (const float*)d_in[2];   // [4000]
    const int*   hlens = (const int*)d_in[3];     // [16]
    const int*   ys    = (const int*)d_in[4];     // [16,100]
    const int*   ylens = (const int*)d_in[5];     // [16]
    float* out = (float*)d_out;

    // workspace layout (bytes)
    char* wsb = (char*)d_ws;
    short* W2      = (short*)(wsb);                         // 4,194,304
    short* A2      = (short*)(wsb + 4194304);               // 13,107,200
    float* PE      = (float*)(wsb + 4194304);               // overlays A2 after lse_mfma: 10,649,600
    float* biasp   = (float*)(wsb + 17301504);              // 16,384
    __hip_bfloat16* Praw = (__hip_bfloat16*)(wsb + 17317888); // 3,276,800
    float* lse_sum = (float*)(wsb + 20594688);              // 51,200
    unsigned char* M     = (unsigned char*)(wsb + 20645888);// 65,536
    unsigned char* canon = (unsigned char*)(wsb + 20711424);// 2,048
    // total ~20.7 MB

    hipLaunchKernelGGL(prep,     dim3(4225),    dim3(256), 0, stream,
                       hs, W, bias, ys, W2, A2, biasp, M, canon, lse_sum, out);
    hipLaunchKernelGGL(lse_mfma, dim3(100, 32), dim3(256), 0, stream,
                       A2, W2, biasp, M, lse_sum, Praw);
    hipLaunchKernelGGL(pexp,     dim3(800),     dim3(256), 0, stream,
                       Praw, lse_sum, canon, PE);
    hipLaunchKernelGGL(ctc_dp,   dim3(16),      dim3(256), 0, stream,
                       PE, hlens, ys, ylens, out);
}

// Round 11
// 242.965 us; speedup vs baseline: 1.1614x; 1.1614x over previous
//
#include <hip/hip_runtime.h>
#include <hip/hip_bf16.h>
#include <math.h>

#define NEGV -1e30f
#define LN2F 0.6931471805599453f

// B=16, T=800, D=512, V=4000 (padded to 4096), Lmax=100, S=201
// M = B*T = 12800 rows.
// GEMM operands are stored PRE-SWIZZLED in MFMA fragment order:
//   A2[rb<100][it<16][wm<2][mi<4][lane<64][8]  (row = rb*128+wm*64+mi*16+(lane&15), k = it*32+(lane>>4)*8)
//   W2[ct<32][it<16][wn<2][ni<4][lane<64][8]   (col = ct*128+wn*64+ni*16+(lane&15), same k)
// so every fragment load is one coalesced global_load_dwordx4 -> no LDS, no barriers.

typedef __attribute__((ext_vector_type(8))) short bf16x8;
typedef __attribute__((ext_vector_type(4))) float f32x4;

__device__ __forceinline__ short f2bf(float x) {
    __hip_bfloat16 h = __float2bfloat16(x);
    return __builtin_bit_cast(short, h);
}

// wave-wide shift-up-by-1 with zero fill on the VALU (DPP wave_shr:1)
__device__ __forceinline__ float shup1(float x) {
    return __builtin_bit_cast(float,
        __builtin_amdgcn_update_dpp(0, __builtin_bit_cast(int, x),
                                    0x138, 0xf, 0xf, true));
}

#define GLD_LDS(g, l) \
    __builtin_amdgcn_global_load_lds( \
        (const __attribute__((address_space(1))) void*)(g), \
        (__attribute__((address_space(3))) void*)(l), 16, 0, 0)

// ---------------------------------------------------------------------------
// prep: W->W2 fragment-swizzle (blocks 0..1023), hs->A2 fragment-swizzle
// (1024..4223), setup tables (4224).
// ---------------------------------------------------------------------------
__global__ __launch_bounds__(256) void prep(
    const float* __restrict__ hs, const float* __restrict__ W,
    const float* __restrict__ bias, const int* __restrict__ ys,
    short* __restrict__ W2, short* __restrict__ A2,
    float* __restrict__ biasp, unsigned char* __restrict__ M,
    unsigned char* __restrict__ canon, float* __restrict__ lse_sum,
    float* __restrict__ out)
{
    __shared__ float tile[32][65];
    __shared__ unsigned char mapl[4096];
    const int bx = blockIdx.x, tid = threadIdx.x;

    if (bx < 1024) {
        // ---- W [512][4000] -> W2 fragment layout (zero-pad cols>=4000) ----
        const int n0 = (bx & 63) * 64;     // 64-col group
        const int k0 = (bx >> 6) * 32;     // 32-k group
        #pragma unroll
        for (int p = 0; p < 8; p++) {
            int idx = p * 256 + tid;
            int k = idx >> 6, n = idx & 63;
            int gn = n0 + n;
            tile[k][n] = (gn < 4000) ? W[(size_t)(k0 + k) * 4000 + gn] : 0.0f;
        }
        __syncthreads();
        const int nn = tid >> 6, lane = tid & 63;
        const int l16 = lane & 15, quad = lane >> 4;
        const int ct = n0 >> 7, wn = (n0 >> 6) & 1, it = k0 >> 5;
        size_t chunk = ((((size_t)ct * 16 + it) * 2 + wn) * 4 + nn) * 64 + lane;
        bf16x8 r;
        #pragma unroll
        for (int j = 0; j < 8; j++) r[j] = f2bf(tile[quad * 8 + j][nn * 16 + l16]);
        *(bf16x8*)(W2 + chunk * 8) = r;
    } else if (bx < 4224) {
        // ---- hs fp32 -> A2 fragment layout ----
        int g = (bx - 1024) * 256 + tid;           // 0..819199
        int lane = g & 63, mi = (g >> 6) & 3, wm = (g >> 8) & 1;
        int it = (g >> 9) & 15, rb = g >> 13;
        int row = rb * 128 + wm * 64 + mi * 16 + (lane & 15);
        int k = it * 32 + (lane >> 4) * 8;
        const float* src = hs + (size_t)row * 512 + k;
        float4 u = *(const float4*)src;
        float4 v = *(const float4*)(src + 4);
        bf16x8 r;
        r[0] = f2bf(u.x); r[1] = f2bf(u.y); r[2] = f2bf(u.z); r[3] = f2bf(u.w);
        r[4] = f2bf(v.x); r[5] = f2bf(v.y); r[6] = f2bf(v.z); r[7] = f2bf(v.w);
        *(bf16x8*)(A2 + (size_t)g * 8) = r;
    } else {
        for (int b = 0; b < 16; b++) {
            for (int i = tid; i < 1024; i += 256)
                ((unsigned int*)mapl)[i] = 0xFFFFFFFFu;
            __syncthreads();
            if (tid == 0) mapl[0] = 0;
            __syncthreads();
            if (tid < 100) mapl[ys[b * 100 + tid]] = (unsigned char)(tid + 1);
            __syncthreads();
            for (int i = tid; i < 1024; i += 256)
                ((unsigned int*)(M + (size_t)b * 4096))[i] = ((const unsigned int*)mapl)[i];
            if (tid < 128) {
                int colc = (tid >= 1 && tid <= 100) ? ys[b * 100 + tid - 1] : 0;
                canon[b * 128 + tid] = mapl[colc];
            }
            __syncthreads();
        }
        for (int i = tid; i < 4096; i += 256)
            biasp[i] = (i < 4000) ? bias[i] : NEGV;
        for (int i = tid; i < 12800; i += 256)
            lse_sum[i] = 0.0f;
        if (tid == 0) out[0] = 0.0f;
    }
}

// ---------------------------------------------------------------------------
// Streaming-sumexp GEMM, LDS-free direct fragment loads, XCD-pinned supertile
// order: xcd = bid&7 owns row tiles {rl*8+xcd}, sweeps ct slowly so its
// ~1.7 MB of A stays hot in the XCD's L2 across all 32 col-tiles.
// grid 3328 x 256 (4 waves).
// ---------------------------------------------------------------------------
__global__ __launch_bounds__(256) void lse_mfma(
    const short* __restrict__ A2,     // fragment layout
    const short* __restrict__ W2,     // fragment layout
    const float* __restrict__ biasp,  // [4096]
    const unsigned char* __restrict__ M,  // [16][4096]
    float* __restrict__ lse_sum,      // [12800]
    __hip_bfloat16* __restrict__ Praw)// [12800][128]
{
    const unsigned int bid = blockIdx.x;
    const unsigned int xcd = bid & 7;
    const unsigned int s = bid >> 3;       // 0..415
    const unsigned int ct = s / 13;        // 0..31  (slow: col tile)
    const unsigned int rl = s - ct * 13;   // 0..12  (fast: row tile within XCD)
    const unsigned int rt = rl * 8 + xcd;  // 0..103
    if (rt >= 100) return;

    const int tid = threadIdx.x;
    const int w = tid >> 6, lane = tid & 63;
    const int quad = lane >> 4, l16 = lane & 15;
    const int wm = w >> 1, wn = w & 1;
    const int row0 = rt * 128;
    const int col0 = ct * 128;

    // it stride = 2*4*64*8 = 4096 shorts; mi/ni stride = 64*8 = 512 shorts
    const short* Abase = A2 + ((size_t)rt * 32 + wm) * 2048 + lane * 8;
    const short* Bbase = W2 + ((size_t)ct * 32 + wn) * 2048 + lane * 8;

    f32x4 acc[4][4];
    #pragma unroll
    for (int mi = 0; mi < 4; mi++)
        #pragma unroll
        for (int ni = 0; ni < 4; ni++) acc[mi][ni] = (f32x4){0.f,0.f,0.f,0.f};

    #pragma unroll 4
    for (int it = 0; it < 16; it++) {
        bf16x8 af[4], bfr[4];
        #pragma unroll
        for (int mi = 0; mi < 4; mi++)
            af[mi] = *(const bf16x8*)(Abase + (size_t)it * 4096 + mi * 512);
        #pragma unroll
        for (int ni = 0; ni < 4; ni++)
            bfr[ni] = *(const bf16x8*)(Bbase + (size_t)it * 4096 + ni * 512);
        #pragma unroll
        for (int mi = 0; mi < 4; mi++)
            #pragma unroll
            for (int ni = 0; ni < 4; ni++)
                acc[mi][ni] = __builtin_amdgcn_mfma_f32_16x16x32_bf16(
                    af[mi], bfr[ni], acc[mi][ni], 0, 0, 0);
    }

    // epilogue: sumexp partials + scatter label-column logits
    const int b0 = row0 / 800;
    const int b1 = (b0 + 1 < 16) ? b0 + 1 : 15;
    const int bbound = (b0 + 1) * 800;
    float sv[16];
    #pragma unroll
    for (int i = 0; i < 16; i++) sv[i] = 0.0f;
    #pragma unroll
    for (int ni = 0; ni < 4; ni++) {
        int col = col0 + wn * 64 + ni * 16 + l16;
        float bj = biasp[col];
        unsigned char sl0 = M[(size_t)b0 * 4096 + col];
        unsigned char sl1 = M[(size_t)b1 * 4096 + col];
        #pragma unroll
        for (int mi = 0; mi < 4; mi++) {
            #pragma unroll
            for (int r = 0; r < 4; r++) {
                int row = row0 + wm * 64 + mi * 16 + quad * 4 + r;
                float v = acc[mi][ni][r] + bj;
                sv[mi * 4 + r] += __expf(v);
                unsigned char sl = (row < bbound) ? sl0 : sl1;
                if (sl != 255)
                    Praw[(size_t)row * 128 + sl] = __float2bfloat16(v);
            }
        }
    }
    #pragma unroll
    for (int off = 1; off < 16; off <<= 1)
        #pragma unroll
        for (int i = 0; i < 16; i++) sv[i] += __shfl_xor(sv[i], off);
    if (l16 == 0) {
        #pragma unroll
        for (int mi = 0; mi < 4; mi++)
            #pragma unroll
            for (int r = 0; r < 4; r++)
                atomicAdd(&lse_sum[row0 + wm * 64 + mi * 16 + quad * 4 + r],
                          sv[mi * 4 + r]);
    }
}

// ---------------------------------------------------------------------------
// pexp: PE[row][s] = exp(Praw[row][st[s]]) * rcp(lse_sum[row]) * 2^11, float.
// ---------------------------------------------------------------------------
__global__ __launch_bounds__(256) void pexp(
    const __hip_bfloat16* __restrict__ Praw,  // [12800][128]
    const float* __restrict__ lse_sum,        // [12800]
    const unsigned char* __restrict__ canon,  // [16][128]
    float* __restrict__ PE)                   // [12800][208]
{
    __shared__ unsigned char st[224];
    __shared__ float scs[16];
    const int bp = blockIdx.x;           // 0..799
    const int b = bp / 50, rr = bp - b * 50;
    const int tid = threadIdx.x;
    const unsigned char* cb = canon + b * 128;
    if (tid < 224) {
        int idx = (tid + 1) >> 1;
        st[tid] = (tid & 1) ? cb[idx < 128 ? idx : 127] : (unsigned char)0;
    }
    const int row0 = b * 800 + rr * 16;
    if (tid < 16) scs[tid] = __builtin_amdgcn_rcpf(lse_sum[row0 + tid]) * 2048.0f;
    __syncthreads();
    for (int item = tid; item < 832; item += 256) {   // 16 rows x 52 float4
        int i = item / 52, sg = item - i * 52;
        int row = row0 + i;
        const __hip_bfloat16* pr = Praw + (size_t)row * 128;
        float sc = scs[i];
        int s0 = sg * 4;
        float4 o;
        o.x = (s0 + 0 <= 200) ? __expf(__bfloat162float(pr[st[s0 + 0]])) * sc : 0.f;
        o.y = (s0 + 1 <= 200) ? __expf(__bfloat162float(pr[st[s0 + 1]])) * sc : 0.f;
        o.z = (s0 + 2 <= 200) ? __expf(__bfloat162float(pr[st[s0 + 2]])) * sc : 0.f;
        o.w = (s0 + 3 <= 200) ? __expf(__bfloat162float(pr[st[s0 + 3]])) * sc : 0.f;
        *(float4*)&PE[(size_t)row * 208 + s0] = o;
    }
}

// ---------------------------------------------------------------------------
// CTC forward DP, probability domain, two steps fused per iteration.
// Staging = contiguous async global_load_lds block copy (53 KB per chunk,
// 16B x 3328 issues, drained by the chunk barrier) -> latency amortized.
// DP wave: 2 contiguous ds_read_b128 per pair (prefetched), DPP neighbors.
// ---------------------------------------------------------------------------
__global__ __launch_bounds__(256) void ctc_dp(
    const float* __restrict__ PE,             // [12800][208]
    const int* __restrict__ hlens,
    const int* __restrict__ ys,
    const int* __restrict__ ylens,
    float* __restrict__ out)
{
    const int b = blockIdx.x, tid = threadIdx.x;
    const int w = tid >> 6, lane = tid & 63;
    __shared__ float emS[2][13376];   // 64 rows x 208 + pad; ~107 KB
    __shared__ float sA[256];

    const float* Pb = PE + (size_t)b * 800 * 208;
    const int hl = hlens[b], L = ylens[b];
    const int t_stop = hl - 1;
    const int C = (t_stop + 63) >> 6;

    const int yb = b * 100;
    float kA = 0.f, kB = 0.f, kH = 0.f;
    if (lane >= 1 && 2 * lane <= 99)
        kA = (ys[yb + 2 * lane] != ys[yb + 2 * lane - 1]) ? 1.f : 0.f;
    if (2 * lane + 1 <= 99)
        kB = (ys[yb + 2 * lane + 1] != ys[yb + 2 * lane]) ? 1.f : 0.f;
    if (lane >= 1 && 2 * lane - 1 <= 99)
        kH = (ys[yb + 2 * lane - 1] != ys[yb + 2 * lane - 2]) ? 1.f : 0.f;
    const float m0  = (lane <= 50) ? 1.f : 0.f;
    const float m13 = (lane <= 49) ? 1.f : 0.f;

    float a0 = 0.f, a1 = 0.f, a2 = 0.f, a3 = 0.f;
    if (w == 0 && lane == 0) {
        a0 = Pb[0];
        a1 = Pb[1];
    }
    int kacc = 0;

    // stage chunk 0: rows t=1..64 = contiguous 53,248 B; 13 x 16B per thread
    {
        const char* src = (const char*)(Pb + 208);
        char* dst = (char*)&emS[0][0];
        #pragma unroll
        for (int j = 0; j < 13; j++) {
            int idx = tid + 256 * j;
            GLD_LDS(src + (size_t)idx * 16, dst + (size_t)idx * 16);
        }
    }
    __syncthreads();

    for (int ch = 0; ch < C; ch++) {
        if (w > 0) {
            int nc = ch + 1;
            if (nc < C) {
                const char* src = (const char*)(Pb + (size_t)(64 * nc + 1) * 208);
                char* dst = (char*)&emS[nc & 1][0];
                const int base = tid - 64;     // 0..191
                #pragma unroll
                for (int j = 0; j < 18; j++) {
                    int idx = base + 192 * j;
                    if (idx < 3328)
                        GLD_LDS(src + (size_t)idx * 16, dst + (size_t)idx * 16);
                }
            }
        } else {
            const float* bb = emS[ch & 1];
            const int t0 = 64 * ch + 1;
            const int soff = 4 * lane;
            if (t0 + 63 <= t_stop) {
                // ---- fast path: 32 fused pairs, 2 b128 reads each ----
                f32x4 e = *(const f32x4*)&bb[0 * 208 + soff];
                f32x4 f = *(const f32x4*)&bb[1 * 208 + soff];
                #pragma unroll
                for (int k = 0; k < 32; k++) {
                    f32x4 en = (f32x4){0.f,0.f,0.f,0.f};
                    f32x4 fn = (f32x4){0.f,0.f,0.f,0.f};
                    if (k < 31) {
                        en = *(const f32x4*)&bb[(2 * k + 2) * 208 + soff];
                        fn = *(const f32x4*)&bb[(2 * k + 3) * 208 + soff];
                    }
                    float pht = shup1(e[3]);
                    float h1 = shup1(a3);
                    float h2 = shup1(a2);
                    float h3 = shup1(a1);
                    float tm1 = fmaf(kH, h3, h1 + h2);
                    float t0v = a0 + h1;
                    float t1v = fmaf(kA, h1, a1 + a0);
                    float t2v = a2 + a1;
                    float t3v = fmaf(kB, a1, a3 + a2);
                    float um1 = pht * tm1;
                    float u0 = e[0] * t0v, u1 = e[1] * t1v;
                    float u2 = e[2] * t2v, u3 = e[3] * t3v;
                    a0 = (f[0] * (u0 + um1)) * m0;
                    a1 = (f[1] * fmaf(kA, um1, u1 + u0)) * m13;
                    a2 = (f[2] * (u2 + u1)) * m13;
                    a3 = (f[3] * fmaf(kB, u1, u3 + u2)) * m13;
                    if ((k & 7) == 7) {
                        int tc = t0 + 2 * k + 1;
                        float lm = fmaxf(fmaxf(a0, a1), fmaxf(a2, a3));
                        int sa1 = (2 * L < tc) ? 2 * L : tc;
                        int sa2 = (int)(2.0f * L * tc / hl);
                        float v1 = __shfl(lm, sa1 >> 2);
                        float v2 = __shfl(lm, sa2 >> 2);
                        float av = fmaxf(v1, v2);
                        int eb = (__float_as_int(av) >> 23) & 0xFF;
                        if (eb != 0 && eb != 255) {
                            int e2i = eb - 127;
                            kacc += e2i;
                            float sc = __int_as_float((127 - e2i) << 23);
                            a0 *= sc; a1 *= sc; a2 *= sc; a3 *= sc;
                        }
                    }
                    e = en; f = fn;
                }
            } else {
                // ---- slow tail: single steps ----
                for (int t = t0; t <= t_stop; t++) {
                    if ((t & 15) == 0) {
                        float lm = fmaxf(fmaxf(a0, a1), fmaxf(a2, a3));
                        int sa1 = (2 * L < t) ? 2 * L : t;
                        int sa2 = (int)(2.0f * L * t / hl);
                        float v1 = __shfl(lm, sa1 >> 2);
                        float v2 = __shfl(lm, sa2 >> 2);
                        float av = fmaxf(v1, v2);
                        int eb = (__float_as_int(av) >> 23) & 0xFF;
                        if (eb != 0 && eb != 255) {
                            int e2i = eb - 127;
                            kacc += e2i;
                            float sc = __int_as_float((127 - e2i) << 23);
                            a0 *= sc; a1 *= sc; a2 *= sc; a3 *= sc;
                        }
                    }
                    f32x4 e = *(const f32x4*)&bb[(t - t0) * 208 + soff];
                    float p3 = shup1(a3);
                    float n0 = (a0 + p3) * e[0];
                    float n1 = fmaf(kA, p3, a1 + a0) * e[1];
                    float n2 = (a2 + a1) * e[2];
                    float n3 = fmaf(kB, a1, a3 + a2) * e[3];
                    a0 = n0 * m0; a1 = n1 * m13; a2 = n2 * m13; a3 = n3 * m13;
                }
            }
        }
        __syncthreads();
    }

    if (w == 0) {
        sA[lane * 4 + 0] = a0; sA[lane * 4 + 1] = a1;
        sA[lane * 4 + 2] = a2; sA[lane * 4 + 3] = a3;
    }
    __syncthreads();

    if (tid == 0) {
        int idx = 2 * L;
        float s = sA[idx] + sA[idx - 1];
        float la = __logf(s) + (float)(kacc - 11 * hl) * LN2F;
        float loss = -la;
        if (!isfinite(loss) || loss >= 1e29f) loss = 0.0f;
        atomicAdd(out, loss * 0.0625f);
    }
}

// ---------------------------------------------------------------------------
extern "C" void kernel_launch(void* const* d_in, const int* in_sizes, int n_in,
                              void* d_out, int out_size, void* d_ws, size_t ws_size,
                              hipStream_t stream)
{
    const float* hs    = (const float*)d_in[0];   // [16,800,512]
    const float* W     = (const float*)d_in[1];   // [512,4000]
    const float* bias  = (const float*)d_in[2];   // [4000]
    const int*   hlens = (const int*)d_in[3];     // [16]
    const int*   ys    = (const int*)d_in[4];     // [16,100]
    const int*   ylens = (const int*)d_in[5];     // [16]
    float* out = (float*)d_out;

    // workspace layout (bytes)
    char* wsb = (char*)d_ws;
    short* W2      = (short*)(wsb);                         // 4,194,304
    short* A2      = (short*)(wsb + 4194304);               // 13,107,200
    float* PE      = (float*)(wsb + 4194304);               // overlays A2 after lse_mfma: 10,649,600 (+slack)
    float* biasp   = (float*)(wsb + 17301504);              // 16,384
    __hip_bfloat16* Praw = (__hip_bfloat16*)(wsb + 17317888); // 3,276,800
    float* lse_sum = (float*)(wsb + 20594688);              // 51,200
    unsigned char* M     = (unsigned char*)(wsb + 20645888);// 65,536
    unsigned char* canon = (unsigned char*)(wsb + 20711424);// 2,048
    // total ~20.7 MB

    hipLaunchKernelGGL(prep,     dim3(4225), dim3(256), 0, stream,
                       hs, W, bias, ys, W2, A2, biasp, M, canon, lse_sum, out);
    hipLaunchKernelGGL(lse_mfma, dim3(3328), dim3(256), 0, stream,
                       A2, W2, biasp, M, lse_sum, Praw);
    hipLaunchKernelGGL(pexp,     dim3(800),  dim3(256), 0, stream,
                       Praw, lse_sum, canon, PE);
    hipLaunchKernelGGL(ctc_dp,   dim3(16),   dim3(256), 0, stream,
                       PE, hlens, ys, ylens, out);
}